// Round 1
// baseline (349.338 us; speedup 1.0000x reference)
//
#include <hip/hip_runtime.h>
#include <math.h>

#define NODEF   64
#define EDGEF_  32
#define HID_    256
#define DEG_    32
#define NNODES_ 64
#define BATCH_  256
#define NTOT    (BATCH_*NNODES_)   // 16384
#define ETOT    (NTOT*DEG_)        // 524288
#define NHEAD   128
#define NFACT_  8

__device__ __forceinline__ float softplus_f(float v) {
    // stable: for large v, log1p(exp(v)) ~ v; for very negative, exp->0, log1p fine
    return v > 20.f ? v : log1pf(expf(v));
}

// ---------------------------------------------------------------------------
// K1: xw_ab[g][0:256] = x[g] @ W1[0:64]   (xi part)
//     xw_ab[g][256:512] = x[g] @ W1[64:128] (xj part)
// 16 nodes per block, 256 threads (thread t owns column t of both halves)
// ---------------------------------------------------------------------------
__global__ __launch_bounds__(256) void k_xw(const float* __restrict__ x,
                                            const float* __restrict__ W1,
                                            float* __restrict__ xw) {
    const int nb = blockIdx.x * 16;
    const int t  = threadIdx.x;
    __shared__ float xs[16][64];
    for (int i = t; i < 16 * 64; i += 256)
        xs[i >> 6][i & 63] = x[(size_t)(nb + (i >> 6)) * 64 + (i & 63)];
    __syncthreads();

    float acc_a[16], acc_b[16];
#pragma unroll
    for (int i = 0; i < 16; i++) { acc_a[i] = 0.f; acc_b[i] = 0.f; }

    for (int k = 0; k < 64; k++) {
        const float wa = W1[k * 256 + t];
        const float wb = W1[(64 + k) * 256 + t];
#pragma unroll
        for (int i = 0; i < 16; i++) {
            const float xv = xs[i][k];
            acc_a[i] = fmaf(xv, wa, acc_a[i]);
            acc_b[i] = fmaf(xv, wb, acc_b[i]);
        }
    }
#pragma unroll
    for (int i = 0; i < 16; i++) {
        xw[(size_t)(nb + i) * 512 + t]       = acc_a[i];
        xw[(size_t)(nb + i) * 512 + 256 + t] = acc_b[i];
    }
}

// ---------------------------------------------------------------------------
// K2: per block = 16 nodes. For each node n (global g):
//   sum_h1[c] = sum_{d<32} relu( xw_a[g][c] + xw_b[dst][c] + ea[e]@W1c[:,c] + b1[c] )
// then in-block: agg[g] = sum_h1 @ W2 + 32*b2   (W2 factored out of segment sum)
// ---------------------------------------------------------------------------
__global__ __launch_bounds__(256) void k_edges(const float* __restrict__ xw,
                                               const float* __restrict__ ea,
                                               const int*   __restrict__ dst,
                                               const float* __restrict__ W1,
                                               const float* __restrict__ b1,
                                               const float* __restrict__ W2,
                                               const float* __restrict__ b2,
                                               float* __restrict__ agg) {
    const int t     = threadIdx.x;
    const int node0 = blockIdx.x * 16;

    __shared__ float w1c[32][256];   // 32 KB
    __shared__ float sh1s[16][256];  // 16 KB
    __shared__ float eas[8][32];     // 1 KB
    __shared__ int   dsts[8];

#pragma unroll
    for (int k = 0; k < 32; k++) w1c[k][t] = W1[(128 + k) * 256 + t];
    const float b1v = b1[t];

    for (int n = 0; n < 16; n++) {
        const int g = node0 + n;
        const float  base  = xw[(size_t)g * 512 + t] + b1v;
        const size_t ebase = (size_t)g * 32;
        float accsum = 0.f;

        for (int grp = 0; grp < 4; grp++) {
            __syncthreads();
            // stage 8 edges' edge_attr (fully coalesced 1 KB) + their dst ids
            eas[t >> 5][t & 31] = ea[ebase * 32 + grp * 256 + t];
            if (t < 8) dsts[t] = dst[ebase + grp * 8 + t];
            __syncthreads();

#pragma unroll
            for (int i = 0; i < 8; i++) {
                const float xb = xw[(size_t)dsts[i] * 512 + 256 + t];
                float eaw = 0.f;
#pragma unroll
                for (int k = 0; k < 32; k++)
                    eaw = fmaf(eas[i][k], w1c[k][t], eaw);
                accsum += fmaxf(base + xb + eaw, 0.f);
            }
        }
        sh1s[n][t] = accsum;
    }
    __syncthreads();

    // agg = sh1 @ W2 + 32*b2
    float acc[16];
#pragma unroll
    for (int i = 0; i < 16; i++) acc[i] = 0.f;
    for (int k = 0; k < 256; k++) {
        const float w = W2[k * 256 + t];
#pragma unroll
        for (int i = 0; i < 16; i++)
            acc[i] = fmaf(sh1s[i][k], w, acc[i]);
    }
    const float bb = 32.f * b2[t];
#pragma unroll
    for (int i = 0; i < 16; i++)
        agg[(size_t)(node0 + i) * 256 + t] = acc[i] + bb;
}

// ---------------------------------------------------------------------------
// K3: heads. One block per batch, 512 threads.
// t in [0,256): pair (edge e = t>>1, sel = t&1 -> mu/sig), 640-dim dot.
// t in [256,272): fact rows (nodes 56..63), 320-dim dot with Wmu2/Wsig2.
// shfl_xor(1) combines alpha/beta within a pair.
// ---------------------------------------------------------------------------
__global__ __launch_bounds__(512) void k_head(const float* __restrict__ x,
                                              const float* __restrict__ agg,
                                              const int*   __restrict__ edges,
                                              const float* __restrict__ high,
                                              const float* __restrict__ Wmu,  const float* __restrict__ bmu,
                                              const float* __restrict__ Wsig, const float* __restrict__ bsig,
                                              const float* __restrict__ Wmu2, const float* __restrict__ bmu2,
                                              const float* __restrict__ Wsig2,const float* __restrict__ bsig2,
                                              float* __restrict__ out) {
    const int b = blockIdx.x;
    const int t = threadIdx.x;

    if (t < 256) {
        const int e   = t >> 1;
        const int sel = t & 1;
        const float* W  = sel ? Wsig : Wmu;
        const float  bi = sel ? bsig[0] : bmu[0];
        const int e0 = edges[e * 2 + 0];
        const int e1 = edges[e * 2 + 1];
        const float* xr0 = x   + (size_t)(b * 64 + e0) * 64;
        const float* ar0 = agg + (size_t)(b * 64 + e0) * 256;
        const float* xr1 = x   + (size_t)(b * 64 + e1) * 64;
        const float* ar1 = agg + (size_t)(b * 64 + e1) * 256;

        float z0 = 0.f, z1 = 0.f;
        for (int k = 0; k < 64; k++)  z0 = fmaf(xr0[k], W[k],        z0);
        for (int k = 0; k < 256; k++) z1 = fmaf(ar0[k], W[64 + k],   z1);
        for (int k = 0; k < 64; k++)  z0 = fmaf(xr1[k], W[320 + k],  z0);
        for (int k = 0; k < 256; k++) z1 = fmaf(ar1[k], W[384 + k],  z1);
        const float z = z0 + z1 + bi;

        const float sp    = softplus_f(z) + 1e-20f;
        const float other = __shfl_xor(sp, 1);
        if (sel == 0)
            out[(size_t)b * 136 + e] = sp / (sp + other) * high[e];
    } else if (t < 272) {
        const int j   = (t - 256) >> 1;
        const int sel = t & 1;
        const float* W  = sel ? Wsig2 : Wmu2;
        const float  bi = sel ? bsig2[0] : bmu2[0];
        const int node = 56 + j;  // last NFACT nodes
        const float* xr = x   + (size_t)(b * 64 + node) * 64;
        const float* ar = agg + (size_t)(b * 64 + node) * 256;

        float z0 = 0.f, z1 = 0.f;
        for (int k = 0; k < 64; k++)  z0 = fmaf(xr[k], W[k],      z0);
        for (int k = 0; k < 256; k++) z1 = fmaf(ar[k], W[64 + k], z1);
        const float z = z0 + z1 + bi;

        const float sp    = softplus_f(z) + 1e-20f;
        const float other = __shfl_xor(sp, 1);
        if (sel == 0)
            out[(size_t)b * 136 + 128 + j] = sp / (sp + other) * high[128 + j];
    }
}

// ---------------------------------------------------------------------------
extern "C" void kernel_launch(void* const* d_in, const int* in_sizes, int n_in,
                              void* d_out, int out_size, void* d_ws, size_t ws_size,
                              hipStream_t stream) {
    const float* x     = (const float*)d_in[0];
    const int*   eidx  = (const int*)  d_in[1];
    const float* ea    = (const float*)d_in[2];
    const int*   edges = (const int*)  d_in[3];
    const float* high  = (const float*)d_in[4];
    const float* W1    = (const float*)d_in[5];
    const float* b1    = (const float*)d_in[6];
    const float* W2    = (const float*)d_in[7];
    const float* b2    = (const float*)d_in[8];
    const float* Wmu   = (const float*)d_in[9];
    const float* bmu   = (const float*)d_in[10];
    const float* Wsig  = (const float*)d_in[11];
    const float* bsig  = (const float*)d_in[12];
    const float* Wmu2  = (const float*)d_in[13];
    const float* bmu2  = (const float*)d_in[14];
    const float* Wsig2 = (const float*)d_in[15];
    const float* bsig2 = (const float*)d_in[16];
    float* out = (float*)d_out;

    float* xw  = (float*)d_ws;                    // 16384*512 f32 = 33.5 MB
    float* agg = xw + (size_t)NTOT * 512;         // 16384*256 f32 = 16.8 MB
    const int* dst = eidx + ETOT;                 // edge_index[1]

    hipLaunchKernelGGL(k_xw,    dim3(NTOT / 16), dim3(256), 0, stream, x, W1, xw);
    hipLaunchKernelGGL(k_edges, dim3(NTOT / 16), dim3(256), 0, stream,
                       xw, ea, dst, W1, b1, W2, b2, agg);
    hipLaunchKernelGGL(k_head,  dim3(BATCH_), dim3(512), 0, stream,
                       x, agg, edges, high,
                       Wmu, bmu, Wsig, bsig, Wmu2, bmu2, Wsig2, bsig2, out);
}

// Round 2
// 156.080 us; speedup vs baseline: 2.2382x; 2.2382x over previous
//
#include <hip/hip_runtime.h>
#include <math.h>

#define NODEF   64
#define EDGEF_  32
#define HID_    256
#define DEG_    32
#define NNODES_ 64
#define BATCH_  256
#define NTOT    (BATCH_*NNODES_)   // 16384
#define ETOT    (NTOT*DEG_)        // 524288
#define NHEAD   128
#define NFACT_  8

typedef __attribute__((ext_vector_type(8))) short short8v;
typedef __attribute__((ext_vector_type(4))) float f32x4;

#define MFMA16(a,b,c) __builtin_amdgcn_mfma_f32_16x16x32_bf16((a),(b),(c),0,0,0)

__device__ __forceinline__ unsigned short f2bf(float f) {
    unsigned int x = __float_as_uint(f);
    return (unsigned short)((x + 0x7fffu + ((x >> 16) & 1u)) >> 16);
}
__device__ __forceinline__ float bf2f(unsigned short h) {
    return __uint_as_float(((unsigned int)h) << 16);
}
// split f32 -> bf16 hi + bf16 lo (3-term MFMA gives ~fp32 accuracy)
__device__ __forceinline__ void pack8(const float* __restrict__ p, short8v& hi, short8v& lo) {
    const f32x4 a = *(const f32x4*)p;
    const f32x4 q = *(const f32x4*)(p + 4);
    float v[8] = {a[0], a[1], a[2], a[3], q[0], q[1], q[2], q[3]};
#pragma unroll
    for (int j = 0; j < 8; j++) {
        const unsigned short h = f2bf(v[j]);
        hi[j] = (short)h;
        lo[j] = (short)f2bf(v[j] - bf2f(h));
    }
}

__device__ __forceinline__ float softplus_f(float v) {
    return v > 20.f ? v : log1pf(expf(v));
}

// ---------------------------------------------------------------------------
// K1: xw[g][0:256]   = x[g] @ W1[0:64]    (xi part)
//     xw[g][256:512] = x[g] @ W1[64:128]  (xj part)
// ---------------------------------------------------------------------------
__global__ __launch_bounds__(256) void k_xw(const float* __restrict__ x,
                                            const float* __restrict__ W1,
                                            float* __restrict__ xw) {
    const int nb = blockIdx.x * 16;
    const int t  = threadIdx.x;
    __shared__ float xs[16][64];
    for (int i = t; i < 16 * 64; i += 256)
        xs[i >> 6][i & 63] = x[(size_t)(nb + (i >> 6)) * 64 + (i & 63)];
    __syncthreads();

    float acc_a[16], acc_b[16];
#pragma unroll
    for (int i = 0; i < 16; i++) { acc_a[i] = 0.f; acc_b[i] = 0.f; }

    for (int k = 0; k < 64; k++) {
        const float wa = W1[k * 256 + t];
        const float wb = W1[(64 + k) * 256 + t];
#pragma unroll
        for (int i = 0; i < 16; i++) {
            const float xv = xs[i][k];
            acc_a[i] = fmaf(xv, wa, acc_a[i]);
            acc_b[i] = fmaf(xv, wb, acc_b[i]);
        }
    }
#pragma unroll
    for (int i = 0; i < 16; i++) {
        xw[(size_t)(nb + i) * 512 + t]       = acc_a[i];
        xw[(size_t)(nb + i) * 512 + 256 + t] = acc_b[i];
    }
}

// ---------------------------------------------------------------------------
// K2 (MFMA): per block = 1 batch (64 nodes, 2048 edges), 16 waves.
// Computes D[ch][edge] = W1c^T . ea^T per node via split-bf16 mfma 16x16x32,
// adds xw_a[node] + xw_b[dst] + b1, relu, sums over the node's 32 edges,
// writes sum_h1[node][ch] (fp32).
// Wave w: nodes (w&7)*8..+7, channel-tiles (w>>3)*8..+7 (16 channels each).
// LDS: xwb fp32 swizzled (bank-conflict-free b128 gather), W1c hi/lo frags,
//      dst local ids. 98 KB.
// ---------------------------------------------------------------------------
__global__ __launch_bounds__(1024) void k_edges2(
    const float* __restrict__ xw, const float* __restrict__ ea,
    const int* __restrict__ dst, const float* __restrict__ W1,
    const float* __restrict__ b1, float* __restrict__ sumh1)
{
    const int b   = blockIdx.x;
    const int tid = threadIdx.x;
    const int l   = tid & 63;
    const int w   = tid >> 6;
    const int g   = l >> 4;
    const int l15 = l & 15;

    __shared__ float          s_xwb[64][256];          // 64 KB, swizzled
    __shared__ unsigned short s_w1c[2][16][64][8];     // 32 KB hi/lo frags
    __shared__ unsigned char  s_dst[2048];             // 2 KB

    for (int idx = tid; idx < 64 * 256; idx += 1024) {
        const int d = idx >> 8, c = idx & 255;
        s_xwb[d][c ^ ((d & 7) << 2)] = xw[(size_t)(b * 64 + d) * 512 + 256 + c];
    }
    for (int idx = tid; idx < 16 * 64 * 8; idx += 1024) {
        const int cht = idx >> 9, rem = idx & 511, ll = rem >> 3, j = rem & 7;
        const int k = ((ll >> 4) << 3) + j, c = cht * 16 + (ll & 15);
        const float v = W1[(128 + k) * 256 + c];
        const unsigned short h = f2bf(v);
        s_w1c[0][cht][ll][j] = h;
        s_w1c[1][cht][ll][j] = f2bf(v - bf2f(h));
    }
    for (int idx = tid; idx < 2048; idx += 1024)
        s_dst[idx] = (unsigned char)(dst[b * 2048 + idx] & 63);
    __syncthreads();

    const int ng = w & 7, chh = w >> 3;

    // register-cache this wave's 8 W1c^T fragments (A operand), hi+lo
    short8v Ah[8], Al[8];
#pragma unroll
    for (int i = 0; i < 8; i++) {
        Ah[i] = *(const short8v*)&s_w1c[0][chh * 8 + i][l][0];
        Al[i] = *(const short8v*)&s_w1c[1][chh * 8 + i][l][0];
    }

    for (int ni = 0; ni < 8; ni++) {
        const int n  = ng * 8 + ni;
        const int d0 = s_dst[n * 32 + l15];
        const int d1 = s_dst[n * 32 + 16 + l15];
        const float* eap = ea + (size_t)(b * 2048 + n * 32) * 32;

        // ea^T fragments (B operand): lane holds ea[edge=et*16+l15][k=g*8+j]
        short8v Bh0, Bl0, Bh1, Bl1;
        pack8(eap + l15 * 32 + g * 8, Bh0, Bl0);
        pack8(eap + (16 + l15) * 32 + g * 8, Bh1, Bl1);

        const size_t xabase = (size_t)(b * 64 + n) * 512;
#pragma unroll
        for (int i = 0; i < 8; i++) {
            const int cht = chh * 8 + i;
            const int cb  = cht * 16 + g * 4;

            f32x4 acc0 = {0.f, 0.f, 0.f, 0.f};
            acc0 = MFMA16(Ah[i], Bh0, acc0);
            acc0 = MFMA16(Ah[i], Bl0, acc0);
            acc0 = MFMA16(Al[i], Bh0, acc0);
            f32x4 acc1 = {0.f, 0.f, 0.f, 0.f};
            acc1 = MFMA16(Ah[i], Bh1, acc1);
            acc1 = MFMA16(Ah[i], Bl1, acc1);
            acc1 = MFMA16(Al[i], Bh1, acc1);

            const f32x4 xa = *(const f32x4*)&xw[xabase + cb];
            const f32x4 bv = *(const f32x4*)&b1[cb];
            const f32x4 wb0 = *(const f32x4*)&s_xwb[d0][cb ^ ((d0 & 7) << 2)];
            const f32x4 wb1 = *(const f32x4*)&s_xwb[d1][cb ^ ((d1 & 7) << 2)];

            float s0 = fmaxf(acc0[0] + xa[0] + bv[0] + wb0[0], 0.f)
                     + fmaxf(acc1[0] + xa[0] + bv[0] + wb1[0], 0.f);
            float s1 = fmaxf(acc0[1] + xa[1] + bv[1] + wb0[1], 0.f)
                     + fmaxf(acc1[1] + xa[1] + bv[1] + wb1[1], 0.f);
            float s2 = fmaxf(acc0[2] + xa[2] + bv[2] + wb0[2], 0.f)
                     + fmaxf(acc1[2] + xa[2] + bv[2] + wb1[2], 0.f);
            float s3 = fmaxf(acc0[3] + xa[3] + bv[3] + wb0[3], 0.f)
                     + fmaxf(acc1[3] + xa[3] + bv[3] + wb1[3], 0.f);

            // sum over the 16 edges held across lanes of this group
#pragma unroll
            for (int m = 1; m < 16; m <<= 1) {
                s0 += __shfl_xor(s0, m);
                s1 += __shfl_xor(s1, m);
                s2 += __shfl_xor(s2, m);
                s3 += __shfl_xor(s3, m);
            }
            if (l15 == 0) {
                f32x4 o = {s0, s1, s2, s3};
                *(f32x4*)&sumh1[(size_t)(b * 64 + n) * 256 + cb] = o;
            }
        }
    }
}

// ---------------------------------------------------------------------------
// K3: agg = sum_h1 @ W2 + 32*b2, split-bf16 MFMA.
// Block = 128 rows x 128 cols; grid = 128 rowchunks x 2 colhalves = 256.
// 512 threads (8 waves), wave = 16-row tile. W2 hi/lo frags in 128 KB LDS.
// ---------------------------------------------------------------------------
__global__ __launch_bounds__(512) void k_agg(
    const float* __restrict__ sumh1, const float* __restrict__ W2,
    const float* __restrict__ b2, float* __restrict__ agg)
{
    const int bx = blockIdx.x;
    const int rcb = bx >> 1, chalf = bx & 1;
    const int tid = threadIdx.x;
    const int l = tid & 63, w = tid >> 6, g = l >> 4, l15 = l & 15;

    __shared__ unsigned short s_w2[2][8][8][64][8];   // 128 KB

    for (int idx = tid; idx < 8 * 8 * 64 * 8; idx += 512) {
        const int ks = idx >> 12, ct = (idx >> 9) & 7, ll = (idx >> 3) & 63, j = idx & 7;
        const int k = ks * 32 + ((ll >> 4) << 3) + j;
        const int c = chalf * 128 + ct * 16 + (ll & 15);
        const float v = W2[k * 256 + c];
        const unsigned short h = f2bf(v);
        s_w2[0][ks][ct][ll][j] = h;
        s_w2[1][ks][ct][ll][j] = f2bf(v - bf2f(h));
    }
    __syncthreads();

    const int row0 = rcb * 128 + w * 16;
    f32x4 acc[8];
#pragma unroll
    for (int ct = 0; ct < 8; ct++) acc[ct] = (f32x4){0.f, 0.f, 0.f, 0.f};

    for (int ks = 0; ks < 8; ks++) {
        short8v Ahh, All;
        pack8(sumh1 + (size_t)(row0 + l15) * 256 + ks * 32 + g * 8, Ahh, All);
#pragma unroll
        for (int ct = 0; ct < 8; ct++) {
            const short8v Bh = *(const short8v*)&s_w2[0][ks][ct][l][0];
            const short8v Bl = *(const short8v*)&s_w2[1][ks][ct][l][0];
            acc[ct] = MFMA16(Ahh, Bh, acc[ct]);
            acc[ct] = MFMA16(Ahh, Bl, acc[ct]);
            acc[ct] = MFMA16(All, Bh, acc[ct]);
        }
    }
#pragma unroll
    for (int ct = 0; ct < 8; ct++) {
        const int c = chalf * 128 + ct * 16 + l15;
        const float bb = 32.f * b2[c];
#pragma unroll
        for (int r = 0; r < 4; r++)
            agg[(size_t)(row0 + g * 4 + r) * 256 + c] = acc[ct][r] + bb;
    }
}

// ---------------------------------------------------------------------------
// K4: heads (unchanged from round 1).
// ---------------------------------------------------------------------------
__global__ __launch_bounds__(512) void k_head(const float* __restrict__ x,
                                              const float* __restrict__ agg,
                                              const int*   __restrict__ edges,
                                              const float* __restrict__ high,
                                              const float* __restrict__ Wmu,  const float* __restrict__ bmu,
                                              const float* __restrict__ Wsig, const float* __restrict__ bsig,
                                              const float* __restrict__ Wmu2, const float* __restrict__ bmu2,
                                              const float* __restrict__ Wsig2,const float* __restrict__ bsig2,
                                              float* __restrict__ out) {
    const int b = blockIdx.x;
    const int t = threadIdx.x;

    if (t < 256) {
        const int e   = t >> 1;
        const int sel = t & 1;
        const float* W  = sel ? Wsig : Wmu;
        const float  bi = sel ? bsig[0] : bmu[0];
        const int e0 = edges[e * 2 + 0];
        const int e1 = edges[e * 2 + 1];
        const float* xr0 = x   + (size_t)(b * 64 + e0) * 64;
        const float* ar0 = agg + (size_t)(b * 64 + e0) * 256;
        const float* xr1 = x   + (size_t)(b * 64 + e1) * 64;
        const float* ar1 = agg + (size_t)(b * 64 + e1) * 256;

        float z0 = 0.f, z1 = 0.f;
        for (int k = 0; k < 64; k++)  z0 = fmaf(xr0[k], W[k],        z0);
        for (int k = 0; k < 256; k++) z1 = fmaf(ar0[k], W[64 + k],   z1);
        for (int k = 0; k < 64; k++)  z0 = fmaf(xr1[k], W[320 + k],  z0);
        for (int k = 0; k < 256; k++) z1 = fmaf(ar1[k], W[384 + k],  z1);
        const float z = z0 + z1 + bi;

        const float sp    = softplus_f(z) + 1e-20f;
        const float other = __shfl_xor(sp, 1);
        if (sel == 0)
            out[(size_t)b * 136 + e] = sp / (sp + other) * high[e];
    } else if (t < 272) {
        const int j   = (t - 256) >> 1;
        const int sel = t & 1;
        const float* W  = sel ? Wsig2 : Wmu2;
        const float  bi = sel ? bsig2[0] : bmu2[0];
        const int node = 56 + j;
        const float* xr = x   + (size_t)(b * 64 + node) * 64;
        const float* ar = agg + (size_t)(b * 64 + node) * 256;

        float z0 = 0.f, z1 = 0.f;
        for (int k = 0; k < 64; k++)  z0 = fmaf(xr[k], W[k],      z0);
        for (int k = 0; k < 256; k++) z1 = fmaf(ar[k], W[64 + k], z1);
        const float z = z0 + z1 + bi;

        const float sp    = softplus_f(z) + 1e-20f;
        const float other = __shfl_xor(sp, 1);
        if (sel == 0)
            out[(size_t)b * 136 + 128 + j] = sp / (sp + other) * high[128 + j];
    }
}

// ---------------------------------------------------------------------------
extern "C" void kernel_launch(void* const* d_in, const int* in_sizes, int n_in,
                              void* d_out, int out_size, void* d_ws, size_t ws_size,
                              hipStream_t stream) {
    const float* x     = (const float*)d_in[0];
    const int*   eidx  = (const int*)  d_in[1];
    const float* ea    = (const float*)d_in[2];
    const int*   edges = (const int*)  d_in[3];
    const float* high  = (const float*)d_in[4];
    const float* W1    = (const float*)d_in[5];
    const float* b1    = (const float*)d_in[6];
    const float* W2    = (const float*)d_in[7];
    const float* b2    = (const float*)d_in[8];
    const float* Wmu   = (const float*)d_in[9];
    const float* bmu   = (const float*)d_in[10];
    const float* Wsig  = (const float*)d_in[11];
    const float* bsig  = (const float*)d_in[12];
    const float* Wmu2  = (const float*)d_in[13];
    const float* bmu2  = (const float*)d_in[14];
    const float* Wsig2 = (const float*)d_in[15];
    const float* bsig2 = (const float*)d_in[16];
    float* out = (float*)d_out;

    // ws layout: xw (16384*512 f32, 33.5 MB) | sumh1 (16384*256 f32, 16.8 MB)
    // agg (16.8 MB) aliases the xw region (xw is dead after k_edges2).
    float* xw    = (float*)d_ws;
    float* sumh1 = xw + (size_t)NTOT * 512;
    float* agg   = xw;
    const int* dst = eidx + ETOT;

    hipLaunchKernelGGL(k_xw,     dim3(NTOT / 16), dim3(256),  0, stream, x, W1, xw);
    hipLaunchKernelGGL(k_edges2, dim3(BATCH_),    dim3(1024), 0, stream,
                       xw, ea, dst, W1, b1, sumh1);
    hipLaunchKernelGGL(k_agg,    dim3(256),       dim3(512),  0, stream,
                       sumh1, W2, b2, agg);
    hipLaunchKernelGGL(k_head,   dim3(BATCH_),    dim3(512),  0, stream,
                       x, agg, edges, high,
                       Wmu, bmu, Wsig, bsig, Wmu2, bmu2, Wsig2, bsig2, out);
}